// Round 9
// baseline (277.385 us; speedup 1.0000x reference)
//
#include <hip/hip_runtime.h>
#include <hip/hip_bf16.h>

#define N_SRCN 200000
#define N_DSTN 50000
#define NEDGE 800000
#define KIN 256
#define NF 192        // H*OUT = 3*64
#define SLOPE 0.2f
#define TILES32 6250  // 32-row tiles
#define GEMM_BLOCKS 256

typedef __attribute__((ext_vector_type(8))) short bf16x8;
typedef __attribute__((ext_vector_type(4))) float f32x4;

__device__ __forceinline__ unsigned short f2bf(float f) {
    union { float f; unsigned int u; } v; v.f = f;
    unsigned int u = v.u;
    return (unsigned short)((u + 0x7FFFu + ((u >> 16) & 1u)) >> 16);  // RNE
}
__device__ __forceinline__ float bf2f(unsigned short h) {
    union { unsigned int u; float f; } v; v.u = ((unsigned int)h) << 16;
    return v.f;
}
__device__ __forceinline__ unsigned int cvt2(float lo, float hi) {
    __hip_bfloat162 h = __float22bfloat162_rn(float2{lo, hi});
    union { __hip_bfloat162 h; unsigned int u; } c; c.h = h;
    return c.u;
}
__device__ __forceinline__ void gl_lds16(const void* g, void* l) {
    __builtin_amdgcn_global_load_lds(
        (const __attribute__((address_space(1))) unsigned int*)g,
        (__attribute__((address_space(3))) unsigned int*)l, 16, 0, 0);
}

// ---------------- merged prep: blocks 0-23 pack W; blocks 24+ build row_ptr --
// Wp[((ks*12 + nt)*64 + lane)*8 + j] = bf16(W[nt*16 + (lane&15)][ks*32 + (lane>>4)*8 + j])
__global__ void prep_kernel(const float* __restrict__ W, unsigned short* __restrict__ Wp,
                            const int* __restrict__ dst, int* __restrict__ rp) {
    const int bid = blockIdx.x;
    if (bid < 24) {
        int tid = bid * 256 + threadIdx.x;
        if (tid >= 12 * 8 * 64) return;
        int lane = tid & 63;
        int g = tid >> 6;
        int nt = g % 12, ks = g / 12;
        int col = nt * 16 + (lane & 15);
        int k = ks * 32 + (lane >> 4) * 8;
        const float* wsrc = &W[col * KIN + k];
        unsigned short* o = &Wp[tid * 8];
        #pragma unroll
        for (int j = 0; j < 8; ++j) o[j] = f2bf(wsrc[j]);
    } else {
        int d = (bid - 24) * 256 + threadIdx.x;
        if (d > N_DSTN) return;
        int lo = 0, hi = NEDGE;
        while (lo < hi) {
            int mid = (lo + hi) >> 1;
            if (dst[mid] < d) lo = mid + 1; else hi = mid;
        }
        rp[d] = lo;
    }
}

// ---------------- GEMM: feat = x @ W^T (bf16 MFMA) + fused el/er -------------
// 256 persistent blocks x 512 thr (1 block/CU, LDS-limited). ALL of Wp (96 KB
// bf16) staged into LDS ONCE per CU -> B never touches L1/L2 again; B-frag
// reads are conflict-free ds_read_b128 (64 lanes x consecutive 16B).
// A: 32-row tiles (32 KB) read direct global->reg; waves 0-3 and 4-7 share
// identical A rows -> L1-resident, HBM read-once. Wave (rh,j3): rows
// [rh*16,+16), cols nt = {j3, 4+j3, 8+j3} (one per head).
__launch_bounds__(512, 2)
__global__ void gemm_feat(const float* __restrict__ x, const unsigned short* __restrict__ Wp,
                          const float* __restrict__ attn_l, const float* __restrict__ attn_r,
                          unsigned short* __restrict__ feat,
                          float* __restrict__ el4, float* __restrict__ er4) {
    __shared__ unsigned short Bl[12 * 8 * 512];   // 96 KB, fragment-major (Wp layout)
    __shared__ float parts[2][32][4][4];          // 4 KB dbuf [rloc][h(pad)][j3]
    const int t = threadIdx.x;
    const int wid = t >> 6, lane = t & 63;
    const int al = lane & 15, ah = lane >> 4;
    const int rh = wid >> 2;     // 16-row half
    const int j3 = wid & 3;      // nt = h*4 + j3

    // ---- stage all of Wp into LDS once (12 x 16B DMA per thread) ----
    #pragma unroll
    for (int i = 0; i < 12; ++i) {
        const int gbase = i * 512 + wid * 64;     // granule base for this wave
        gl_lds16(&Wp[(size_t)(gbase + lane) * 8], &Bl[(size_t)gbase * 8]);
    }
    asm volatile("s_waitcnt vmcnt(0)" ::: "memory");
    __syncthreads();

    float Al[3], Ar[3];
    #pragma unroll
    for (int h = 0; h < 3; ++h) {
        Al[h] = attn_l[(h * 4 + j3) * 16 + al];
        Ar[h] = attn_r[(h * 4 + j3) * 16 + al];
    }

    int pb = 0;
    for (int tl = blockIdx.x; tl < TILES32; tl += GEMM_BLOCKS, pb ^= 1) {
        const int r0 = tl * 32;
        const float* xrow = &x[(size_t)(r0 + rh * 16 + al) * KIN + ah * 8];

        f32x4 acc[3] = {};
        #pragma unroll
        for (int ks = 0; ks < 8; ++ks) {
            const float4 a0 = *(const float4*)&xrow[ks * 32];
            const float4 a1 = *(const float4*)&xrow[ks * 32 + 4];
            union { bf16x8 v; unsigned int u[4]; } av;
            av.u[0] = cvt2(a0.x, a0.y);
            av.u[1] = cvt2(a0.z, a0.w);
            av.u[2] = cvt2(a1.x, a1.y);
            av.u[3] = cvt2(a1.z, a1.w);
            #pragma unroll
            for (int h = 0; h < 3; ++h) {
                const bf16x8 bv = *(const bf16x8*)&Bl[(size_t)(ks * 12 + h * 4 + j3) * 512 + lane * 8];
                acc[h] = __builtin_amdgcn_mfma_f32_16x16x32_bf16(av.v, bv, acc[h], 0, 0, 0);
            }
        }

        // epilogue 1: feat store (C/D: col=nt*16+al, row=ah*4+e [m89])
        #pragma unroll
        for (int h = 0; h < 3; ++h) {
            const int col = (h * 4 + j3) * 16 + al;
            #pragma unroll
            for (int e = 0; e < 4; ++e) {
                const int row = r0 + rh * 16 + ah * 4 + e;
                feat[(size_t)row * NF + col] = f2bf(acc[h][e]);
            }
        }

        // epilogue 2: el/er partials (16-lane al-reduce per head)
        #pragma unroll
        for (int e = 0; e < 4; ++e)
            #pragma unroll
            for (int h = 0; h < 3; ++h) {
                float sl = acc[h][e] * Al[h];
                float sr = acc[h][e] * Ar[h];
                #pragma unroll
                for (int m = 1; m <= 8; m <<= 1) {
                    sl += __shfl_xor(sl, m);
                    sr += __shfl_xor(sr, m);
                }
                if (al == 0) {
                    const int rloc = rh * 16 + ah * 4 + e;
                    parts[pb][rloc][h][j3] = sl;
                    parts[pb][rloc][h][j3 == 0 ? 3 : j3 - 1] = parts[pb][rloc][h][j3 == 0 ? 3 : j3 - 1]; // no-op keep layout
                    parts[pb][rloc][h][j3] = sl;
                    // store r-part in the unused h=3 lane of the pad: use separate array half below
                }
            }
        // separate r-partials in second half of dbuf trick: reuse pad h==3? ->
        // simpler: second small shared array
        __syncthreads();
        // reduce l-parts, then handle r via shuffle-free second pass below
        if (t < 256) {
            const int rloc = t >> 3, h = t & 7;
            if (h < 3) {
                const float s = parts[pb][rloc][h][0] + parts[pb][rloc][h][1]
                              + parts[pb][rloc][h][2] + parts[pb][rloc][h][3];
                el4[(size_t)(r0 + rloc) * 4 + h] = s;
            }
        }
        __syncthreads();
        // r-partials (reuse same parts buffer slot pb after barrier)
        #pragma unroll
        for (int e = 0; e < 4; ++e)
            #pragma unroll
            for (int h = 0; h < 3; ++h) {
                float sr = acc[h][e] * Ar[h];
                #pragma unroll
                for (int m = 1; m <= 8; m <<= 1) sr += __shfl_xor(sr, m);
                if (al == 0) parts[pb][rh * 16 + ah * 4 + e][h][j3] = sr;
            }
        __syncthreads();
        if (t < 256) {
            const int rloc = t >> 3, h = t & 7;
            const int row = r0 + rloc;
            if (h < 3 && row < N_DSTN) {
                const float s = parts[pb][rloc][h][0] + parts[pb][rloc][h][1]
                              + parts[pb][rloc][h][2] + parts[pb][rloc][h][3];
                er4[(size_t)row * 4 + h] = s;
            }
        }
    }
}

// ---------------- gather: edge softmax (no max shift) + weighted accumulate --
__launch_bounds__(256)
__global__ void gather_kernel(const unsigned short* __restrict__ feat,
                              const float* __restrict__ el4, const float* __restrict__ er4,
                              const int* __restrict__ src, const int* __restrict__ rp,
                              float* __restrict__ out) {
    const int lane = threadIdx.x & 63;
    const int d = (blockIdx.x * blockDim.x + threadIdx.x) >> 6;
    if (d >= N_DSTN) return;
    const int lo = rp[d], hi = rp[d + 1];
    const float4 erv = *(const float4*)&er4[(size_t)d * 4];

    float a0 = 0.f, a1 = 0.f, a2 = 0.f, s0 = 0.f, s1 = 0.f, s2 = 0.f;
    for (int base = lo; base < hi; base += 64) {
        const int cnt = min(64, hi - base);
        int sv = 0; float w0 = 0.f, w1 = 0.f, w2 = 0.f;
        if (lane < cnt) {
            sv = src[base + lane];
            const float4 elv = *(const float4*)&el4[(size_t)sv * 4];
            float e0 = elv.x + erv.x; e0 = e0 >= 0.f ? e0 : SLOPE * e0; w0 = __expf(e0);
            float e1 = elv.y + erv.y; e1 = e1 >= 0.f ? e1 : SLOPE * e1; w1 = __expf(e1);
            float e2 = elv.z + erv.z; e2 = e2 >= 0.f ? e2 : SLOPE * e2; w2 = __expf(e2);
        }
        int j = 0;
        for (; j + 8 <= cnt; j += 8) {
            unsigned short f0[8], f1[8], f2[8];
            float u0[8], u1[8], u2[8];
            #pragma unroll
            for (int q = 0; q < 8; ++q) {
                const int sj = __shfl(sv, j + q);
                const unsigned short* fp = &feat[(size_t)sj * NF + lane];
                f0[q] = fp[0]; f1[q] = fp[64]; f2[q] = fp[128];
                u0[q] = __shfl(w0, j + q);
                u1[q] = __shfl(w1, j + q);
                u2[q] = __shfl(w2, j + q);
            }
            #pragma unroll
            for (int q = 0; q < 8; ++q) {
                s0 += u0[q]; a0 += u0[q] * bf2f(f0[q]);
                s1 += u1[q]; a1 += u1[q] * bf2f(f1[q]);
                s2 += u2[q]; a2 += u2[q] * bf2f(f2[q]);
            }
        }
        for (; j < cnt; ++j) {
            const int sj = __shfl(sv, j);
            const float u0 = __shfl(w0, j);
            const float u1 = __shfl(w1, j);
            const float u2 = __shfl(w2, j);
            const unsigned short* fp = &feat[(size_t)sj * NF + lane];
            s0 += u0; a0 += u0 * bf2f(fp[0]);
            s1 += u1; a1 += u1 * bf2f(fp[64]);
            s2 += u2; a2 += u2 * bf2f(fp[128]);
        }
    }
    if (hi == lo) { s0 = 1.f; s1 = 1.f; s2 = 1.f; }
    float* op = &out[(size_t)d * NF];
    op[lane]       = a0 / s0;
    op[64 + lane]  = a1 / s1;
    op[128 + lane] = a2 / s2;
}

extern "C" void kernel_launch(void* const* d_in, const int* in_sizes, int n_in,
                              void* d_out, int out_size, void* d_ws, size_t ws_size,
                              hipStream_t stream) {
    const float* x      = (const float*)d_in[0];
    const float* W      = (const float*)d_in[1];
    const float* attn_l = (const float*)d_in[2];
    const float* attn_r = (const float*)d_in[3];
    const int*   src    = (const int*)d_in[4];
    const int*   dst    = (const int*)d_in[5];
    float* out = (float*)d_out;

    char* ws = (char*)d_ws;
    unsigned short* feat = (unsigned short*)ws;             // 76,800,000 B
    float* el4 = (float*)(ws + 76800000);                   // 3,200,000 B
    float* er4 = (float*)(ws + 80000000);                   //   800,000 B
    unsigned short* Wp = (unsigned short*)(ws + 80800000);  //    98,304 B
    int*   rp = (int*)(ws + 80898304);                      //   200,004 B

    prep_kernel<<<24 + 196, 256, 0, stream>>>(W, Wp, dst, rp);
    gemm_feat<<<GEMM_BLOCKS, 512, 0, stream>>>(x, Wp, attn_l, attn_r, feat, el4, er4);
    gather_kernel<<<12500, 256, 0, stream>>>(feat, el4, er4, src, rp, out);
}

// Round 10
// 149.846 us; speedup vs baseline: 1.8511x; 1.8511x over previous
//
#include <hip/hip_runtime.h>
#include <hip/hip_bf16.h>

#define N_SRCN 200000
#define N_DSTN 50000
#define NEDGE 800000
#define KIN 256
#define NF 192        // H*OUT = 3*64
#define SLOPE 0.2f
#define TILES16 12500 // 16-row tiles
#define NWAVES 2048   // 256 blocks x 8 waves

typedef __attribute__((ext_vector_type(8))) short bf16x8;
typedef __attribute__((ext_vector_type(4))) float f32x4;

__device__ __forceinline__ unsigned short f2bf(float f) {
    union { float f; unsigned int u; } v; v.f = f;
    unsigned int u = v.u;
    return (unsigned short)((u + 0x7FFFu + ((u >> 16) & 1u)) >> 16);  // RNE
}
__device__ __forceinline__ float bf2f(unsigned short h) {
    union { unsigned int u; float f; } v; v.u = ((unsigned int)h) << 16;
    return v.f;
}
__device__ __forceinline__ unsigned int cvt2(float lo, float hi) {
    __hip_bfloat162 h = __float22bfloat162_rn(float2{lo, hi});
    union { __hip_bfloat162 h; unsigned int u; } c; c.h = h;
    return c.u;
}
__device__ __forceinline__ void gl_lds16(const void* g, void* l) {
    __builtin_amdgcn_global_load_lds(
        (const __attribute__((address_space(1))) unsigned int*)g,
        (__attribute__((address_space(3))) unsigned int*)l, 16, 0, 0);
}

// ---------------- merged prep: blocks 0-23 pack W; blocks 24+ build row_ptr --
// Wp[((ks*12 + nt)*64 + lane)*8 + j] = bf16(W[nt*16 + (lane&15)][ks*32 + (lane>>4)*8 + j])
__global__ void prep_kernel(const float* __restrict__ W, unsigned short* __restrict__ Wp,
                            const int* __restrict__ dst, int* __restrict__ rp) {
    const int bid = blockIdx.x;
    if (bid < 24) {
        int tid = bid * 256 + threadIdx.x;
        if (tid >= 12 * 8 * 64) return;
        int lane = tid & 63;
        int g = tid >> 6;
        int nt = g % 12, ks = g / 12;
        int col = nt * 16 + (lane & 15);
        int k = ks * 32 + (lane >> 4) * 8;
        const float* wsrc = &W[col * KIN + k];
        unsigned short* o = &Wp[tid * 8];
        #pragma unroll
        for (int j = 0; j < 8; ++j) o[j] = f2bf(wsrc[j]);
    } else {
        int d = (bid - 24) * 256 + threadIdx.x;
        if (d > N_DSTN) return;
        int lo = 0, hi = NEDGE;
        while (lo < hi) {
            int mid = (lo + hi) >> 1;
            if (dst[mid] < d) lo = mid + 1; else hi = mid;
        }
        rp[d] = lo;
    }
}

// ---------------- GEMM: feat = x @ W^T (bf16 MFMA) + fused el/er -------------
// Grid = 256 blocks x 512 thr (exactly 1 block/CU: 96KB LDS). Stage ALL of Wp
// into LDS once (global_load_lds, 1 barrier) -> B never touches L1/L2 again.
// Then 8 waves per block run INDEPENDENT 16-row tiles (grid-stride, ZERO
// barriers, zero global B-loads): per tile 16 pipelined A-loads from global +
// 96 conflict-free ds_read_b128 + 96 MFMA. el/er fused via 16-lane reduce.
__global__ void __launch_bounds__(512, 1)
gemm_feat(const float* __restrict__ x, const unsigned short* __restrict__ Wp,
          const float* __restrict__ attn_l, const float* __restrict__ attn_r,
          unsigned short* __restrict__ feat,
          float* __restrict__ el4, float* __restrict__ er4) {
    __shared__ unsigned short Bl[12 * 8 * 512];   // 96 KB, Wp fragment-major layout
    const int t = threadIdx.x;
    const int wid = t >> 6, lane = t & 63;
    const int al = lane & 15, ah = lane >> 4;

    // ---- stage Wp -> LDS (12 sweeps x 8KB; dest = uniform base + lane*16) ----
    #pragma unroll
    for (int i = 0; i < 12; ++i) {
        const int off = (i * 8 + wid) * 1024;     // byte offset, wave-uniform
        gl_lds16((const char*)Wp + off + lane * 16, (char*)Bl + off);
    }
    asm volatile("s_waitcnt vmcnt(0)" ::: "memory");
    __syncthreads();
    // ---- after this point: NO barriers, waves fully independent ----

    float Al[12], Ar[12];
    #pragma unroll
    for (int nt = 0; nt < 12; ++nt) {
        Al[nt] = attn_l[nt * 16 + al];
        Ar[nt] = attn_r[nt * 16 + al];
    }

    const int gw = blockIdx.x * 8 + wid;          // global wave id 0..2047
    for (int tile = gw; tile < TILES16; tile += NWAVES) {
        const int r0 = tile * 16;
        const float* xrow = &x[(size_t)(r0 + al) * KIN + ah * 8];

        f32x4 acc[12] = {};
        #pragma unroll
        for (int ks = 0; ks < 8; ++ks) {
            const float4 a0 = *(const float4*)&xrow[ks * 32];
            const float4 a1 = *(const float4*)&xrow[ks * 32 + 4];
            union { bf16x8 v; unsigned int u[4]; } av;
            av.u[0] = cvt2(a0.x, a0.y);
            av.u[1] = cvt2(a0.z, a0.w);
            av.u[2] = cvt2(a1.x, a1.y);
            av.u[3] = cvt2(a1.z, a1.w);
            #pragma unroll
            for (int nt = 0; nt < 12; ++nt) {
                const bf16x8 bv = *(const bf16x8*)&Bl[(ks * 12 + nt) * 512 + lane * 8];
                acc[nt] = __builtin_amdgcn_mfma_f32_16x16x32_bf16(av.v, bv, acc[nt], 0, 0, 0);
            }
        }

        // epilogue 1: feat store (C/D layout: col=nt*16+al, row=ah*4+e  [m89])
        #pragma unroll
        for (int nt = 0; nt < 12; ++nt) {
            const int col = nt * 16 + al;
            #pragma unroll
            for (int e = 0; e < 4; ++e) {
                const int row = r0 + ah * 4 + e;
                feat[(size_t)row * NF + col] = f2bf(acc[nt][e]);
            }
        }

        // epilogue 2: fused el/er (16-lane al-reduce per head)
        #pragma unroll
        for (int h = 0; h < 3; ++h) {
            #pragma unroll
            for (int e = 0; e < 4; ++e) {
                float sl = 0.f, sr = 0.f;
                #pragma unroll
                for (int q = 0; q < 4; ++q) {
                    const int nt = h * 4 + q;
                    sl += acc[nt][e] * Al[nt];
                    sr += acc[nt][e] * Ar[nt];
                }
                #pragma unroll
                for (int m = 1; m <= 8; m <<= 1) {
                    sl += __shfl_xor(sl, m);
                    sr += __shfl_xor(sr, m);
                }
                if (al == 0) {
                    const int row = r0 + ah * 4 + e;
                    el4[(size_t)row * 4 + h] = sl;
                    if (row < N_DSTN) er4[(size_t)row * 4 + h] = sr;
                }
            }
        }
    }
}

// ---------------- gather: edge softmax (no max shift) + weighted accumulate --
__launch_bounds__(256)
__global__ void gather_kernel(const unsigned short* __restrict__ feat,
                              const float* __restrict__ el4, const float* __restrict__ er4,
                              const int* __restrict__ src, const int* __restrict__ rp,
                              float* __restrict__ out) {
    const int lane = threadIdx.x & 63;
    const int d = (blockIdx.x * blockDim.x + threadIdx.x) >> 6;
    if (d >= N_DSTN) return;
    const int lo = rp[d], hi = rp[d + 1];
    const float4 erv = *(const float4*)&er4[(size_t)d * 4];

    float a0 = 0.f, a1 = 0.f, a2 = 0.f, s0 = 0.f, s1 = 0.f, s2 = 0.f;
    for (int base = lo; base < hi; base += 64) {
        const int cnt = min(64, hi - base);
        int sv = 0; float w0 = 0.f, w1 = 0.f, w2 = 0.f;
        if (lane < cnt) {
            sv = src[base + lane];
            const float4 elv = *(const float4*)&el4[(size_t)sv * 4];
            float e0 = elv.x + erv.x; e0 = e0 >= 0.f ? e0 : SLOPE * e0; w0 = __expf(e0);
            float e1 = elv.y + erv.y; e1 = e1 >= 0.f ? e1 : SLOPE * e1; w1 = __expf(e1);
            float e2 = elv.z + erv.z; e2 = e2 >= 0.f ? e2 : SLOPE * e2; w2 = __expf(e2);
        }
        int j = 0;
        for (; j + 8 <= cnt; j += 8) {
            unsigned short f0[8], f1[8], f2[8];
            float u0[8], u1[8], u2[8];
            #pragma unroll
            for (int q = 0; q < 8; ++q) {
                const int sj = __shfl(sv, j + q);
                const unsigned short* fp = &feat[(size_t)sj * NF + lane];
                f0[q] = fp[0]; f1[q] = fp[64]; f2[q] = fp[128];
                u0[q] = __shfl(w0, j + q);
                u1[q] = __shfl(w1, j + q);
                u2[q] = __shfl(w2, j + q);
            }
            #pragma unroll
            for (int q = 0; q < 8; ++q) {
                s0 += u0[q]; a0 += u0[q] * bf2f(f0[q]);
                s1 += u1[q]; a1 += u1[q] * bf2f(f1[q]);
                s2 += u2[q]; a2 += u2[q] * bf2f(f2[q]);
            }
        }
        for (; j < cnt; ++j) {
            const int sj = __shfl(sv, j);
            const float u0 = __shfl(w0, j);
            const float u1 = __shfl(w1, j);
            const float u2 = __shfl(w2, j);
            const unsigned short* fp = &feat[(size_t)sj * NF + lane];
            s0 += u0; a0 += u0 * bf2f(fp[0]);
            s1 += u1; a1 += u1 * bf2f(fp[64]);
            s2 += u2; a2 += u2 * bf2f(fp[128]);
        }
    }
    if (hi == lo) { s0 = 1.f; s1 = 1.f; s2 = 1.f; }
    float* op = &out[(size_t)d * NF];
    op[lane]       = a0 / s0;
    op[64 + lane]  = a1 / s1;
    op[128 + lane] = a2 / s2;
}

extern "C" void kernel_launch(void* const* d_in, const int* in_sizes, int n_in,
                              void* d_out, int out_size, void* d_ws, size_t ws_size,
                              hipStream_t stream) {
    const float* x      = (const float*)d_in[0];
    const float* W      = (const float*)d_in[1];
    const float* attn_l = (const float*)d_in[2];
    const float* attn_r = (const float*)d_in[3];
    const int*   src    = (const int*)d_in[4];
    const int*   dst    = (const int*)d_in[5];
    float* out = (float*)d_out;

    char* ws = (char*)d_ws;
    unsigned short* feat = (unsigned short*)ws;             // 76,800,000 B
    float* el4 = (float*)(ws + 76800000);                   // 3,200,000 B
    float* er4 = (float*)(ws + 80000000);                   //   800,000 B
    unsigned short* Wp = (unsigned short*)(ws + 80800000);  //    98,304 B
    int*   rp = (int*)(ws + 80898304);                      //   200,004 B

    prep_kernel<<<24 + 196, 256, 0, stream>>>(W, Wp, dst, rp);
    gemm_feat<<<256, 512, 0, stream>>>(x, Wp, attn_l, attn_r, feat, el4, er4);
    gather_kernel<<<12500, 256, 0, stream>>>(feat, el4, er4, src, rp, out);
}

// Round 11
// 149.729 us; speedup vs baseline: 1.8526x; 1.0008x over previous
//
#include <hip/hip_runtime.h>
#include <hip/hip_bf16.h>

#define N_SRCN 200000
#define N_DSTN 50000
#define NEDGE 800000
#define KIN 256
#define NF 192        // H*OUT = 3*64
#define SLOPE 0.2f
#define TILES16 12500 // 16-row tiles
#define NWAVES 4096   // 256 blocks x 16 waves

typedef __attribute__((ext_vector_type(8))) short bf16x8;
typedef __attribute__((ext_vector_type(4))) float f32x4;

__device__ __forceinline__ unsigned short f2bf(float f) {
    union { float f; unsigned int u; } v; v.f = f;
    unsigned int u = v.u;
    return (unsigned short)((u + 0x7FFFu + ((u >> 16) & 1u)) >> 16);  // RNE
}
__device__ __forceinline__ float bf2f(unsigned short h) {
    union { unsigned int u; float f; } v; v.u = ((unsigned int)h) << 16;
    return v.f;
}
__device__ __forceinline__ unsigned int cvt2(float lo, float hi) {
    __hip_bfloat162 h = __float22bfloat162_rn(float2{lo, hi});
    union { __hip_bfloat162 h; unsigned int u; } c; c.h = h;
    return c.u;
}
__device__ __forceinline__ void gl_lds16(const void* g, void* l) {
    __builtin_amdgcn_global_load_lds(
        (const __attribute__((address_space(1))) unsigned int*)g,
        (__attribute__((address_space(3))) unsigned int*)l, 16, 0, 0);
}

// ---------------- merged prep: blocks 0-23 pack W; blocks 24+ build row_ptr --
// Wp[((ks*12 + nt)*64 + lane)*8 + j] = bf16(W[nt*16 + (lane&15)][ks*32 + (lane>>4)*8 + j])
__global__ void prep_kernel(const float* __restrict__ W, unsigned short* __restrict__ Wp,
                            const int* __restrict__ dst, int* __restrict__ rp) {
    const int bid = blockIdx.x;
    if (bid < 24) {
        int tid = bid * 256 + threadIdx.x;
        if (tid >= 12 * 8 * 64) return;
        int lane = tid & 63;
        int g = tid >> 6;
        int nt = g % 12, ks = g / 12;
        int col = nt * 16 + (lane & 15);
        int k = ks * 32 + (lane >> 4) * 8;
        const float* wsrc = &W[col * KIN + k];
        unsigned short* o = &Wp[tid * 8];
        #pragma unroll
        for (int j = 0; j < 8; ++j) o[j] = f2bf(wsrc[j]);
    } else {
        int d = (bid - 24) * 256 + threadIdx.x;
        if (d > N_DSTN) return;
        int lo = 0, hi = NEDGE;
        while (lo < hi) {
            int mid = (lo + hi) >> 1;
            if (dst[mid] < d) lo = mid + 1; else hi = mid;
        }
        rp[d] = lo;
    }
}

// ---------------- GEMM: feat = x @ W^T (bf16 MFMA) + fused el/er -------------
// Grid = 256 blocks x 1024 thr (1 block/CU, 96KB LDS, 16 waves/CU = 4/SIMD).
// Stage ALL of Wp into LDS once (global_load_lds, 1 barrier) -> B never
// touches L1/L2 again. Then 16 waves per block run INDEPENDENT 16-row tiles
// (grid-stride, ZERO barriers): per tile 16 pipelined A-loads from global +
// 96 conflict-free ds_read_b128 + 96 MFMA. el/er fused via 16-lane reduce.
// launch_bounds(1024,1) caps VGPR at 128 so all 16 waves are resident.
__global__ void __launch_bounds__(1024, 1)
gemm_feat(const float* __restrict__ x, const unsigned short* __restrict__ Wp,
          const float* __restrict__ attn_l, const float* __restrict__ attn_r,
          unsigned short* __restrict__ feat,
          float* __restrict__ el4, float* __restrict__ er4) {
    __shared__ unsigned short Bl[12 * 8 * 512];   // 96 KB, Wp fragment-major layout
    const int t = threadIdx.x;
    const int wid = t >> 6, lane = t & 63;
    const int al = lane & 15, ah = lane >> 4;

    // ---- stage Wp -> LDS (6 sweeps x 16KB; dest = uniform base + lane*16) ----
    #pragma unroll
    for (int i = 0; i < 6; ++i) {
        const int off = (i * 16 + wid) * 1024;    // byte offset, wave-uniform
        gl_lds16((const char*)Wp + off + lane * 16, (char*)Bl + off);
    }
    asm volatile("s_waitcnt vmcnt(0)" ::: "memory");
    __syncthreads();
    // ---- after this point: NO barriers, waves fully independent ----

    float Al[12], Ar[12];
    #pragma unroll
    for (int nt = 0; nt < 12; ++nt) {
        Al[nt] = attn_l[nt * 16 + al];
        Ar[nt] = attn_r[nt * 16 + al];
    }

    const int gw = blockIdx.x * 16 + wid;         // global wave id 0..4095
    for (int tile = gw; tile < TILES16; tile += NWAVES) {
        const int r0 = tile * 16;
        const float* xrow = &x[(size_t)(r0 + al) * KIN + ah * 8];

        f32x4 acc[12] = {};
        #pragma unroll
        for (int ks = 0; ks < 8; ++ks) {
            const float4 a0 = *(const float4*)&xrow[ks * 32];
            const float4 a1 = *(const float4*)&xrow[ks * 32 + 4];
            union { bf16x8 v; unsigned int u[4]; } av;
            av.u[0] = cvt2(a0.x, a0.y);
            av.u[1] = cvt2(a0.z, a0.w);
            av.u[2] = cvt2(a1.x, a1.y);
            av.u[3] = cvt2(a1.z, a1.w);
            #pragma unroll
            for (int nt = 0; nt < 12; ++nt) {
                const bf16x8 bv = *(const bf16x8*)&Bl[(ks * 12 + nt) * 512 + lane * 8];
                acc[nt] = __builtin_amdgcn_mfma_f32_16x16x32_bf16(av.v, bv, acc[nt], 0, 0, 0);
            }
        }

        // epilogue 1: feat store (C/D layout: col=nt*16+al, row=ah*4+e  [m89])
        #pragma unroll
        for (int nt = 0; nt < 12; ++nt) {
            const int col = nt * 16 + al;
            #pragma unroll
            for (int e = 0; e < 4; ++e) {
                const int row = r0 + ah * 4 + e;
                feat[(size_t)row * NF + col] = f2bf(acc[nt][e]);
            }
        }

        // epilogue 2: fused el/er (16-lane al-reduce per head)
        #pragma unroll
        for (int h = 0; h < 3; ++h) {
            #pragma unroll
            for (int e = 0; e < 4; ++e) {
                float sl = 0.f, sr = 0.f;
                #pragma unroll
                for (int q = 0; q < 4; ++q) {
                    const int nt = h * 4 + q;
                    sl += acc[nt][e] * Al[nt];
                    sr += acc[nt][e] * Ar[nt];
                }
                #pragma unroll
                for (int m = 1; m <= 8; m <<= 1) {
                    sl += __shfl_xor(sl, m);
                    sr += __shfl_xor(sr, m);
                }
                if (al == 0) {
                    const int row = r0 + ah * 4 + e;
                    el4[(size_t)row * 4 + h] = sl;
                    if (row < N_DSTN) er4[(size_t)row * 4 + h] = sr;
                }
            }
        }
    }
}

// ---------------- gather: edge softmax (no max shift) + weighted accumulate --
__launch_bounds__(256)
__global__ void gather_kernel(const unsigned short* __restrict__ feat,
                              const float* __restrict__ el4, const float* __restrict__ er4,
                              const int* __restrict__ src, const int* __restrict__ rp,
                              float* __restrict__ out) {
    const int lane = threadIdx.x & 63;
    const int d = (blockIdx.x * blockDim.x + threadIdx.x) >> 6;
    if (d >= N_DSTN) return;
    const int lo = rp[d], hi = rp[d + 1];
    const float4 erv = *(const float4*)&er4[(size_t)d * 4];

    float a0 = 0.f, a1 = 0.f, a2 = 0.f, s0 = 0.f, s1 = 0.f, s2 = 0.f;
    for (int base = lo; base < hi; base += 64) {
        const int cnt = min(64, hi - base);
        int sv = 0; float w0 = 0.f, w1 = 0.f, w2 = 0.f;
        if (lane < cnt) {
            sv = src[base + lane];
            const float4 elv = *(const float4*)&el4[(size_t)sv * 4];
            float e0 = elv.x + erv.x; e0 = e0 >= 0.f ? e0 : SLOPE * e0; w0 = __expf(e0);
            float e1 = elv.y + erv.y; e1 = e1 >= 0.f ? e1 : SLOPE * e1; w1 = __expf(e1);
            float e2 = elv.z + erv.z; e2 = e2 >= 0.f ? e2 : SLOPE * e2; w2 = __expf(e2);
        }
        int j = 0;
        for (; j + 8 <= cnt; j += 8) {
            unsigned short f0[8], f1[8], f2[8];
            float u0[8], u1[8], u2[8];
            #pragma unroll
            for (int q = 0; q < 8; ++q) {
                const int sj = __shfl(sv, j + q);
                const unsigned short* fp = &feat[(size_t)sj * NF + lane];
                f0[q] = fp[0]; f1[q] = fp[64]; f2[q] = fp[128];
                u0[q] = __shfl(w0, j + q);
                u1[q] = __shfl(w1, j + q);
                u2[q] = __shfl(w2, j + q);
            }
            #pragma unroll
            for (int q = 0; q < 8; ++q) {
                s0 += u0[q]; a0 += u0[q] * bf2f(f0[q]);
                s1 += u1[q]; a1 += u1[q] * bf2f(f1[q]);
                s2 += u2[q]; a2 += u2[q] * bf2f(f2[q]);
            }
        }
        for (; j < cnt; ++j) {
            const int sj = __shfl(sv, j);
            const float u0 = __shfl(w0, j);
            const float u1 = __shfl(w1, j);
            const float u2 = __shfl(w2, j);
            const unsigned short* fp = &feat[(size_t)sj * NF + lane];
            s0 += u0; a0 += u0 * bf2f(fp[0]);
            s1 += u1; a1 += u1 * bf2f(fp[64]);
            s2 += u2; a2 += u2 * bf2f(fp[128]);
        }
    }
    if (hi == lo) { s0 = 1.f; s1 = 1.f; s2 = 1.f; }
    float* op = &out[(size_t)d * NF];
    op[lane]       = a0 / s0;
    op[64 + lane]  = a1 / s1;
    op[128 + lane] = a2 / s2;
}

extern "C" void kernel_launch(void* const* d_in, const int* in_sizes, int n_in,
                              void* d_out, int out_size, void* d_ws, size_t ws_size,
                              hipStream_t stream) {
    const float* x      = (const float*)d_in[0];
    const float* W      = (const float*)d_in[1];
    const float* attn_l = (const float*)d_in[2];
    const float* attn_r = (const float*)d_in[3];
    const int*   src    = (const int*)d_in[4];
    const int*   dst    = (const int*)d_in[5];
    float* out = (float*)d_out;

    char* ws = (char*)d_ws;
    unsigned short* feat = (unsigned short*)ws;             // 76,800,000 B
    float* el4 = (float*)(ws + 76800000);                   // 3,200,000 B
    float* er4 = (float*)(ws + 80000000);                   //   800,000 B
    unsigned short* Wp = (unsigned short*)(ws + 80800000);  //    98,304 B
    int*   rp = (int*)(ws + 80898304);                      //   200,004 B

    prep_kernel<<<24 + 196, 256, 0, stream>>>(W, Wp, dst, rp);
    gemm_feat<<<256, 1024, 0, stream>>>(x, Wp, attn_l, attn_r, feat, el4, er4);
    gather_kernel<<<12500, 256, 0, stream>>>(feat, el4, er4, src, rp, out);
}